// Round 1
// baseline (104.219 us; speedup 1.0000x reference)
//
#include <hip/hip_runtime.h>

#define N_    32
#define CIN   128
#define H_    56
#define W_    56
#define COUT  256
#define GROUPS 4
#define CPG   32      // in-channels per group
#define OPG   64      // out-channels per group
#define CDIM  64

#define TH     4              // output rows per block
#define HALO_R (TH + 2)       // 6
#define HALO_C (W_ + 2)       // 58
#define NPIX   (TH * W_)      // 224
#define NT     (NPIX / 16)    // 14 pixel tiles
#define XPLANE (HALO_R * HALO_C)  // 348 halo pixels

typedef __bf16 bf16x8 __attribute__((ext_vector_type(8)));
typedef float  f32x4  __attribute__((ext_vector_type(4)));

__global__ __launch_bounds__(256, 2) void ctx_conv_kernel(
    const float* __restrict__ x, const float* __restrict__ c,
    const float* __restrict__ wgt, const float* __restrict__ bias,
    const float* __restrict__ cw, float* __restrict__ out)
{
    // LDS: weights [tap][ocL][ic] (36864 B), x tile [ic>>3][pix][ic&7] (22272 B)
    __shared__ __align__(16) __bf16 w_lds[9][OPG][CPG];
    __shared__ __align__(16) __bf16 x_lds[4][XPLANE][8];
    __shared__ float ctx_lds[OPG];

    const int ht  = blockIdx.x;   // 0..13  (4-row strip)
    const int g   = blockIdx.y;   // 0..3
    const int n   = blockIdx.z;   // 0..31
    const int tid = threadIdx.x;
    const int h0  = ht * TH;

    // ---- stage weights (coalesced: j walks [ocL][ic][tap] = global layout) ----
    {
        const float* wg = wgt + (size_t)g * (OPG * CPG * 9);
        for (int j = tid; j < OPG * CPG * 9; j += 256) {
            int ocL  = j / (CPG * 9);
            int r    = j - ocL * (CPG * 9);
            int ic   = r / 9;
            int tap  = r - ic * 9;           // kh*3+kw
            w_lds[tap][ocL][ic] = (__bf16)wg[j];
        }
    }
    // ---- stage x strip with zero halo ----
    {
        const float* xg = x + ((size_t)n * CIN + g * CPG) * (H_ * W_);
        for (int j = tid; j < CPG * XPLANE; j += 256) {
            int ic = j / XPLANE;
            int r2 = j - ic * XPLANE;        // halo pixel index
            int hr = r2 / HALO_C;
            int wc = r2 - hr * HALO_C;
            int hg = h0 - 1 + hr;            // global row
            int wg2 = wc - 1;                // global col
            float v = 0.f;
            if ((unsigned)hg < (unsigned)H_ && (unsigned)wg2 < (unsigned)W_)
                v = xg[ic * (H_ * W_) + hg * W_ + wg2];
            x_lds[ic >> 3][r2][ic & 7] = (__bf16)v;
        }
    }
    // ---- ctx[n, oc] + bias, exact fp32 ----
    if (tid < OPG) {
        int oc = g * OPG + tid;
        float s = bias[oc];
        const float* cn  = c  + n * CDIM;
        const float* cwo = cw + oc * CDIM;
        #pragma unroll
        for (int d = 0; d < CDIM; ++d) s += cn[d] * cwo[d];
        ctx_lds[tid] = s;
    }
    __syncthreads();

    const int wv   = tid >> 6;     // wave id = oc-16-tile
    const int lane = tid & 63;
    const int l15  = lane & 15;
    const int kh4  = lane >> 4;    // k-half: ic group of 8

    // A fragments: lane holds A[row=l15][k=kh4*8+e] = W[ocL=wv*16+l15][ic=k][tap]
    bf16x8 a[9];
    #pragma unroll
    for (int k = 0; k < 9; ++k)
        a[k] = *(const bf16x8*)&w_lds[k][wv * 16 + l15][kh4 * 8];

    // D rows this lane writes: oc = base + kh4*4 + r
    float ctxv[4];
    #pragma unroll
    for (int r = 0; r < 4; ++r)
        ctxv[r] = ctx_lds[wv * 16 + kh4 * 4 + r];

    float* outb = out + ((size_t)n * COUT + g * OPG + wv * 16 + kh4 * 4) * (H_ * W_)
                      + h0 * W_;

    for (int t = 0; t < NT; ++t) {
        int p  = t * 16 + l15;       // pixel within strip (B col & D col)
        int pr = p / W_;
        int pc = p - pr * W_;
        f32x4 acc = {0.f, 0.f, 0.f, 0.f};
        #pragma unroll
        for (int kh = 0; kh < 3; ++kh) {
            #pragma unroll
            for (int kw = 0; kw < 3; ++kw) {
                // B[k=ic][col=p] = x[ic][h0+pr+kh-1][pc+kw-1]  (halo origin -1,-1)
                const bf16x8 b = *(const bf16x8*)&x_lds[kh4][(pr + kh) * HALO_C + (pc + kw)][0];
                acc = __builtin_amdgcn_mfma_f32_16x16x32_bf16(a[kh * 3 + kw], b, acc, 0, 0, 0);
            }
        }
        #pragma unroll
        for (int r = 0; r < 4; ++r)
            outb[(size_t)r * (H_ * W_) + p] = acc[r] + ctxv[r];
    }
}

extern "C" void kernel_launch(void* const* d_in, const int* in_sizes, int n_in,
                              void* d_out, int out_size, void* d_ws, size_t ws_size,
                              hipStream_t stream) {
    const float* x    = (const float*)d_in[0];
    const float* c    = (const float*)d_in[1];
    const float* wgt  = (const float*)d_in[2];
    const float* bias = (const float*)d_in[3];
    const float* cw   = (const float*)d_in[4];
    float* out = (float*)d_out;

    dim3 grid(H_ / TH, GROUPS, N_);   // (14, 4, 32)
    ctx_conv_kernel<<<grid, 256, 0, stream>>>(x, c, wgt, bias, cw, out);
}

// Round 2
// 59.041 us; speedup vs baseline: 1.7652x; 1.7652x over previous
//
#include <hip/hip_runtime.h>

#define N_    32
#define CIN   128
#define H_    56
#define W_    56
#define HW_   (H_ * W_)
#define COUT  256
#define GROUPS 4
#define CPG   32      // in-channels per group
#define OPG   64      // out-channels per group
#define CDIM  64

#define TH     8              // output rows per block
#define HALO_R (TH + 2)       // 10
#define HALO_C (W_ + 2)       // 58
#define NPIX   (TH * W_)      // 448
#define NT     (NPIX / 16)    // 28 pixel tiles (14 per wave-half)
#define XPLANE (HALO_R * HALO_C)  // 580 halo pixels

typedef __bf16 bf16x8 __attribute__((ext_vector_type(8)));
typedef float  f32x4  __attribute__((ext_vector_type(4)));

// ---------- pre-kernel 1: ctx[n][oc] = bias[oc] + c[n,:] . cw[oc,:] ----------
__global__ void ctx_kernel(const float* __restrict__ c, const float* __restrict__ bias,
                           const float* __restrict__ cw, float* __restrict__ gctx) {
    const int n  = blockIdx.x;
    const int oc = threadIdx.x;
    const float* cn  = c  + n * CDIM;   // wave-uniform -> s_loads
    const float* cwo = cw + oc * CDIM;
    float s = bias[oc];
    #pragma unroll
    for (int d = 0; d < CDIM; ++d) s += cn[d] * cwo[d];
    gctx[n * COUT + oc] = s;
}

// ---------- pre-kernel 2: weight fp32 [oc][ic][3][3] -> bf16 [g][tap][kh4][ocL][8] ----------
__global__ void wconv_kernel(const float* __restrict__ wgt, __bf16* __restrict__ wbf) {
    int j = blockIdx.x * 256 + threadIdx.x;       // output linear index, coalesced write
    int e   = j & 7;
    int r   = j >> 3;
    int ocL = r & 63;  r >>= 6;
    int o   = r & 3;   r >>= 2;                   // ic octet (kh4)
    int tap = r % 9;
    int g   = r / 9;
    int ic  = o * 8 + e;
    wbf[j] = (__bf16)wgt[((g * OPG + ocL) * CPG + ic) * 9 + tap];
}

// ---------- main kernel ----------
__global__ __launch_bounds__(512, 4) void ctx_conv_kernel(
    const float* __restrict__ x, const __bf16* __restrict__ wbf,
    const float* __restrict__ gctx, float* __restrict__ out)
{
    // w_lds[tap][kh4][ocL][e]: a-frag read = 16B contiguous per lane, floor conflicts
    __shared__ __align__(16) __bf16 w_lds[9][4][OPG][8];   // 36864 B
    __shared__ __align__(16) __bf16 x_lds[4][XPLANE][8];   // 37120 B

    const int ht  = blockIdx.x;   // 0..6  (8-row strip)
    const int g   = blockIdx.y;   // 0..3
    const int n   = blockIdx.z;   // 0..31
    const int tid = threadIdx.x;  // 0..511
    const int h0  = ht * TH;

    // ---- stage weights: linear 16B copy of pre-permuted bf16 block ----
    {
        const uint4* src = (const uint4*)(wbf + (size_t)g * (9 * 4 * OPG * 8));
        uint4* dst = (uint4*)&w_lds[0][0][0][0];
        #pragma unroll
        for (int j = tid; j < 9 * 4 * OPG * 8 * 2 / 16; j += 512)   // 2304 chunks
            dst[j] = src[j];
    }
    // ---- stage x strip with zero halo: job = (ic octet, halo pixel) ----
    {
        const float* xg = x + ((size_t)n * CIN + g * CPG) * HW_;
        for (int j = tid; j < 4 * XPLANE; j += 512) {
            int o  = j / XPLANE;             // ic octet
            int r2 = j - o * XPLANE;         // halo pixel
            int hr = r2 / HALO_C;
            int wc = r2 - hr * HALO_C;
            int hg  = h0 - 1 + hr;
            int wg2 = wc - 1;
            bool valid = ((unsigned)hg < (unsigned)H_) && ((unsigned)wg2 < (unsigned)W_);
            const float* src = xg + (size_t)(o * 8) * HW_ + hg * W_ + wg2;
            bf16x8 v;
            #pragma unroll
            for (int e = 0; e < 8; ++e)
                v[e] = (__bf16)(valid ? src[(size_t)e * HW_] : 0.f);
            *(bf16x8*)&x_lds[o][r2][0] = v;   // coalesced, conflict-free
        }
    }
    __syncthreads();

    const int wv     = tid >> 6;       // 0..7
    const int octile = wv & 3;         // oc 16-tile
    const int phalf  = wv >> 2;        // pixel half
    const int lane   = tid & 63;
    const int l15    = lane & 15;
    const int kh4    = lane >> 4;      // ic octet / D row group

    // A fragments: lane holds A[row=l15][k=kh4*8+e] = W[ocL][ic=kh4*8+e][tap]
    bf16x8 a[9];
    #pragma unroll
    for (int tap = 0; tap < 9; ++tap)
        a[tap] = *(const bf16x8*)&w_lds[tap][kh4][octile * 16 + l15][0];

    const int ocb = g * OPG + octile * 16 + kh4 * 4;   // first of 4 oc rows
    float ctxv[4];
    #pragma unroll
    for (int r = 0; r < 4; ++r)
        ctxv[r] = gctx[n * COUT + ocb + r];

    float* outb = out + ((size_t)n * COUT + ocb) * HW_ + h0 * W_;

    const int t0 = phalf * (NT / 2);
    #pragma unroll 2
    for (int t = t0; t < t0 + NT / 2; ++t) {
        int p  = t * 16 + l15;           // pixel within strip (B col & D col)
        int pr = p / W_;
        int pc = p - pr * W_;
        f32x4 acc = {0.f, 0.f, 0.f, 0.f};
        #pragma unroll
        for (int kh = 0; kh < 3; ++kh) {
            #pragma unroll
            for (int kw = 0; kw < 3; ++kw) {
                const bf16x8 b = *(const bf16x8*)&x_lds[kh4][(pr + kh) * HALO_C + (pc + kw)][0];
                acc = __builtin_amdgcn_mfma_f32_16x16x32_bf16(a[kh * 3 + kw], b, acc, 0, 0, 0);
            }
        }
        #pragma unroll
        for (int r = 0; r < 4; ++r)
            outb[(size_t)r * HW_ + p] = acc[r] + ctxv[r];
    }
}

extern "C" void kernel_launch(void* const* d_in, const int* in_sizes, int n_in,
                              void* d_out, int out_size, void* d_ws, size_t ws_size,
                              hipStream_t stream) {
    const float* x    = (const float*)d_in[0];
    const float* c    = (const float*)d_in[1];
    const float* wgt  = (const float*)d_in[2];
    const float* bias = (const float*)d_in[3];
    const float* cw   = (const float*)d_in[4];
    float* out = (float*)d_out;

    float*  gctx = (float*)d_ws;                          // 32 KB
    __bf16* wbf  = (__bf16*)((char*)d_ws + 32768);        // 144 KB

    ctx_kernel<<<dim3(N_), 256, 0, stream>>>(c, bias, cw, gctx);
    wconv_kernel<<<dim3((COUT * CPG * 9) / 256), 256, 0, stream>>>(wgt, wbf);

    dim3 grid(H_ / TH, GROUPS, N_);   // (7, 4, 32)
    ctx_conv_kernel<<<grid, 512, 0, stream>>>(x, wbf, gctx, out);
}